// Round 5
// baseline (162.675 us; speedup 1.0000x reference)
//
#include <hip/hip_runtime.h>

// Problem constants from the reference: x is (N, T, F) fp32.
constexpr int N_ = 64;
constexpr int T_ = 4096;
constexpr int F_ = 64;
constexpr int F4 = F_ / 4;   // 16 vec4 per (n,t) row

typedef float fvec4 __attribute__((ext_vector_type(4)));

// Reflect-pad + validity-mask gather.
//   src = rel<0 ? -rel : (rel<L ? rel : 2L-rel-2), clipped to [0, T-1]
//   out[n,t,:] = t < L+p0+p1 ? x[n,src,:] : 0
//
// Layout: 16 threads (one vec4 each) per (n,t) row -> 256B contiguous
// load+store per row; each wave covers 4 consecutive t rows (1KB) per step.
//
// ROWS_PER_THREAD=8 with loads-issued-first: 8 independent loads in flight
// per lane before any dependent store — tests whether the kernel was
// load-latency-bound (2 rows/thread gave only 2 overlapped load/store pairs).
constexpr int ROWS_PER_THREAD = 8;
constexpr int T_PER_BLOCK = 16 * ROWS_PER_THREAD;   // 128 t-rows per block

__global__ __launch_bounds__(256) void pad_variable_kernel(
    const fvec4* __restrict__ x,
    const int*   __restrict__ lens,
    const int*   __restrict__ pad,   // (2, N): pad[n]=pad0, pad[N_+n]=pad1
    fvec4*       __restrict__ out,
    int Tp)
{
    const int tid  = threadIdx.x;
    const int f4   = tid & (F4 - 1);      // vec4 index within F
    const int trow = tid >> 4;            // 0..15 within block
    const int n    = blockIdx.y;          // wave-uniform -> lens/pad via s_load

    const int L  = lens[n];
    const int p0 = pad[n];
    const int p1 = pad[N_ + n];
    const int Lv = L + p0 + p1;           // valid length

    const fvec4* xn   = x   + (size_t)n * T_ * F4;
    fvec4*       outn = out + (size_t)n * Tp * F4;

    const int t0 = blockIdx.x * T_PER_BLOCK + trow;

    fvec4 v[ROWS_PER_THREAD];

    // Phase 1: issue all independent loads (predicated; zeros otherwise).
#pragma unroll
    for (int r = 0; r < ROWS_PER_THREAD; ++r) {
        const int t = t0 + r * 16;
        const int rel = t - p0;
        int src = (rel < 0) ? -rel : ((rel < L) ? rel : (2 * L - rel - 2));
        src = min(max(src, 0), T_ - 1);
        v[r] = (fvec4)(0.f);
        if (t < Lv && t < Tp) {
            v[r] = xn[(size_t)src * F4 + f4];
        }
    }

    // Phase 2: stores.
#pragma unroll
    for (int r = 0; r < ROWS_PER_THREAD; ++r) {
        const int t = t0 + r * 16;
        if (t < Tp) {
            outn[(size_t)t * F4 + f4] = v[r];
        }
    }
}

extern "C" void kernel_launch(void* const* d_in, const int* in_sizes, int n_in,
                              void* d_out, int out_size, void* d_ws, size_t ws_size,
                              hipStream_t stream) {
    const float* x    = (const float*)d_in[0];
    const int*   lens = (const int*)d_in[1];
    const int*   pad  = (const int*)d_in[2];
    // Recover Tp from out_size (out has N*Tp*F elements) — no D2H read needed.
    const int Tp = out_size / (N_ * F_);

    dim3 block(256);
    dim3 grid((Tp + T_PER_BLOCK - 1) / T_PER_BLOCK, N_);
    hipLaunchKernelGGL(pad_variable_kernel, grid, block, 0, stream,
                       (const fvec4*)x, lens, pad, (fvec4*)d_out, Tp);
}

// Round 6
// 151.713 us; speedup vs baseline: 1.0723x; 1.0723x over previous
//
#include <hip/hip_runtime.h>

// Problem constants from the reference: x is (N, T, F) fp32.
constexpr int N_ = 64;
constexpr int T_ = 4096;
constexpr int F_ = 64;
constexpr int F4 = F_ / 4;   // 16 vec4 per (n,t) row

typedef float fvec4 __attribute__((ext_vector_type(4)));

// Reflect-pad + validity-mask gather.
//   src = rel<0 ? -rel : (rel<L ? rel : 2L-rel-2), clipped to [0, T-1]
//   out[n,t,:] = t < L+p0+p1 ? x[n,src,:] : 0
//
// Layout: 16 threads (one vec4 each) per (n,t) row; each wave covers 4
// consecutive t rows (1KB contiguous) per memory instruction.
//
// ROWS_PER_THREAD=4, loads-first: 4 independent loads in flight per lane
// (vs 2 in round 4) while keeping VGPRs low enough for 6-8 waves/SIMD.
// ROWS=8 regressed (108 VGPR -> 4 waves/SIMD, bench +17us): TLP loss beat
// the ILP gain. ROWS=4 targets the knee of the TLP*ILP product.
constexpr int ROWS_PER_THREAD = 4;
constexpr int T_PER_BLOCK = 16 * ROWS_PER_THREAD;   // 64 t-rows per block

__global__ __launch_bounds__(256) void pad_variable_kernel(
    const fvec4* __restrict__ x,
    const int*   __restrict__ lens,
    const int*   __restrict__ pad,   // (2, N): pad[n]=pad0, pad[N_+n]=pad1
    fvec4*       __restrict__ out,
    int Tp)
{
    const int tid  = threadIdx.x;
    const int f4   = tid & (F4 - 1);      // vec4 index within F
    const int trow = tid >> 4;            // 0..15 within block
    const int n    = blockIdx.y;          // wave-uniform -> lens/pad via s_load

    const int L  = lens[n];
    const int p0 = pad[n];
    const int p1 = pad[N_ + n];
    const int Lv = L + p0 + p1;           // valid length

    const fvec4* xn   = x   + (size_t)n * T_ * F4;
    fvec4*       outn = out + (size_t)n * Tp * F4;

    const int t0 = blockIdx.x * T_PER_BLOCK + trow;

    fvec4 v[ROWS_PER_THREAD];

    // Phase 1: issue all independent (predicated) loads.
#pragma unroll
    for (int r = 0; r < ROWS_PER_THREAD; ++r) {
        const int t = t0 + r * 16;
        const int rel = t - p0;
        int src = (rel < 0) ? -rel : ((rel < L) ? rel : (2 * L - rel - 2));
        src = min(max(src, 0), T_ - 1);
        v[r] = (fvec4)(0.f);
        if (t < Lv && t < Tp) {
            v[r] = xn[(size_t)src * F4 + f4];
        }
    }

    // Phase 2: stores.
#pragma unroll
    for (int r = 0; r < ROWS_PER_THREAD; ++r) {
        const int t = t0 + r * 16;
        if (t < Tp) {
            outn[(size_t)t * F4 + f4] = v[r];
        }
    }
}

extern "C" void kernel_launch(void* const* d_in, const int* in_sizes, int n_in,
                              void* d_out, int out_size, void* d_ws, size_t ws_size,
                              hipStream_t stream) {
    const float* x    = (const float*)d_in[0];
    const int*   lens = (const int*)d_in[1];
    const int*   pad  = (const int*)d_in[2];
    // Recover Tp from out_size (out has N*Tp*F elements) — no D2H read needed.
    const int Tp = out_size / (N_ * F_);

    dim3 block(256);
    dim3 grid((Tp + T_PER_BLOCK - 1) / T_PER_BLOCK, N_);
    hipLaunchKernelGGL(pad_variable_kernel, grid, block, 0, stream,
                       (const fvec4*)x, lens, pad, (fvec4*)d_out, Tp);
}